// Round 12
// baseline (1738.664 us; speedup 1.0000x reference)
//
#include <hip/hip_runtime.h>

#define N_PTS   16384
#define M_CENT  1024
#define K_SMP   32
#define C_FEAT  64
#define NCELL   512

using bf16x8 = __attribute__((ext_vector_type(8))) short;
using s16x4  = __attribute__((ext_vector_type(4))) short;
using f32x4  = __attribute__((ext_vector_type(4))) float;

__device__ inline short f2bf(float f) {            // f32 -> bf16 RNE
    unsigned u = __float_as_uint(f);
    u += 0x7fffu + ((u >> 16) & 1u);
    return (short)(u >> 16);
}

// ---------------------------------------------------------------------------
// DPP max-reductions (VALU pipe) — r10-proven.
#define DPP_SHR1 0x111
#define DPP_SHR2 0x112
#define DPP_SHR4 0x114
#define DPP_SHR8 0x118
#define DPP_BC15 0x142
#define DPP_BC31 0x143

template<int CTRL, int RM>
__device__ __forceinline__ float dppmax(float v) {
    int o = __builtin_amdgcn_update_dpp(__float_as_int(v), __float_as_int(v),
                                        CTRL, RM, 0xF, false);
    return fmaxf(v, __int_as_float(o));
}

__device__ __forceinline__ float wave64_fmax(float v) {
    v = dppmax<DPP_SHR1, 0xF>(v);
    v = dppmax<DPP_SHR2, 0xF>(v);
    v = dppmax<DPP_SHR4, 0xF>(v);
    v = dppmax<DPP_SHR8, 0xF>(v);
    v = dppmax<DPP_BC15, 0xA>(v);
    v = dppmax<DPP_BC31, 0xC>(v);
    return __int_as_float(__builtin_amdgcn_readlane(__float_as_int(v), 63));
}

__device__ __forceinline__ float row16_fmax(float v) {
    v = dppmax<DPP_SHR1, 0xF>(v);
    v = dppmax<DPP_SHR2, 0xF>(v);
    v = dppmax<DPP_SHR4, 0xF>(v);
    v = dppmax<DPP_SHR8, 0xF>(v);
    return __int_as_float(__builtin_amdgcn_readlane(__float_as_int(v), 15));
}

// ---------------------------------------------------------------------------
// Hilbert cell id (8x8x8 = 512 cells). Order affects only speed.
__device__ inline int hcell_of(float x, float y, float z) {
    int xi = (int)(x * 8.0f); xi = xi < 0 ? 0 : (xi > 7 ? 7 : xi);
    int yi = (int)(y * 8.0f); yi = yi < 0 ? 0 : (yi > 7 ? 7 : yi);
    int zi = (int)(z * 8.0f); zi = zi < 0 ? 0 : (zi > 7 ? 7 : zi);
    unsigned X[3] = {(unsigned)xi, (unsigned)yi, (unsigned)zi};
#pragma unroll
    for (unsigned Q = 4; Q > 1; Q >>= 1) {
        unsigned P = Q - 1;
#pragma unroll
        for (int i = 0; i < 3; ++i) {
            if (X[i] & Q) X[0] ^= P;
            else { unsigned t = (X[0] ^ X[i]) & P; X[0] ^= t; X[i] ^= t; }
        }
    }
    X[1] ^= X[0]; X[2] ^= X[1];
    unsigned t = 0;
#pragma unroll
    for (unsigned Q = 4; Q > 1; Q >>= 1)
        if (X[2] & Q) t ^= Q - 1;
    X[0] ^= t; X[1] ^= t; X[2] ^= t;
    int h = 0;
#pragma unroll
    for (int q = 2; q >= 0; --q)
        h = (h << 3) | (((X[0] >> q) & 1) << 2) | (((X[1] >> q) & 1) << 1) | ((X[2] >> q) & 1);
    return h;
}

// ---------------------------------------------------------------------------
__global__ __launch_bounds__(1024) void hist_kernel(
    const float* __restrict__ xyz, int* __restrict__ ghist)
{
    __shared__ int h[NCELL];
    const int b = blockIdx.x, tid = threadIdx.x;
    if (tid < NCELL) h[tid] = 0;
    __syncthreads();
    const float* P = xyz + (size_t)b * N_PTS * 3;
    for (int i = 0; i < 16; ++i) {
        const int p = tid + (i << 10);
        atomicAdd(&h[hcell_of(P[p*3], P[p*3+1], P[p*3+2])], 1);
    }
    __syncthreads();
    if (tid < NCELL) ghist[b * NCELL + tid] = h[tid];
}

__global__ __launch_bounds__(NCELL) void scan_kernel(
    const int* __restrict__ ghist, int* __restrict__ gbase)
{
    __shared__ int h[NCELL];
    const int b = blockIdx.x, t = threadIdx.x;
    h[t] = ghist[b * NCELL + t];
    __syncthreads();
    int s = 0;
    for (int i = 0; i < t; ++i) s += h[i];
    gbase[b * NCELL + t] = s;
}

__global__ __launch_bounds__(1024) void scatter_kernel(
    const float* __restrict__ xyz, int* __restrict__ gbase,
    float4* __restrict__ gsxyz)
{
    const int b = blockIdx.x, tid = threadIdx.x;
    const float* P = xyz + (size_t)b * N_PTS * 3;
    for (int i = 0; i < 16; ++i) {
        const int p = tid + (i << 10);
        float x = P[p*3], y = P[p*3+1], z = P[p*3+2];
        int c = hcell_of(x, y, z);
        int pos = atomicAdd(&gbase[b * NCELL + c], 1);
        gsxyz[(size_t)b * N_PTS + pos] = make_float4(x, y, z, __int_as_float(p));
    }
}

// ---------------------------------------------------------------------------
// FPS, bit-exact pruned. r12 = r10's single-barrier parity structure with a
// shortened post-barrier chain:
//  - publish ONE float4 slot {x,y,z,value} (+ side pay[] = norig, off-chain);
//  - post-barrier: one ds_read_b128 -> candidate coords live in registers ->
//    row16 DPP max on .w -> ballot -> winner slot -> cx,cy,cz via 3 readlanes
//    (replaces r10's second dependent LDS read + u64 tie-loop);
//  - rare equal-value tie across slots resolved via pay (max norig = smallest
//    original idx; norig unique per point) -> idx stays bit-exact;
//  - pass-1 per-lane predicated (if(need)): exec-masked lanes issue no LDS
//    bank work; split base pointers keep all 16 ds_read offsets immediate.
__global__ __launch_bounds__(1024) void fps_kernel(
    const float* __restrict__ xyz,
    const float4* __restrict__ gsxyz,
    float* __restrict__ newxyz_out,
    float* __restrict__ idxf_out)
{
#pragma clang fp contract(off)
    const int b = blockIdx.x, tid = threadIdx.x;
    const int wid = tid >> 6, lane = tid & 63;
    const float4* S = gsxyz + (size_t)b * N_PTS;

    __shared__ float2 xy[16 * 1024];              // 128 KB
    __shared__ float4 wslot[2][16];               // parity double-buffer
    __shared__ unsigned wpay[2][16];

    float z[16], mind[16];
    unsigned npk[8];                              // norig = 16383-orig, 2/reg
    float lox = 1e30f, hix = -1e30f, loy = 1e30f, hiy = -1e30f, loz = 1e30f, hiz = -1e30f;
#pragma unroll
    for (int i = 0; i < 16; ++i) {
        const float4 v = S[tid * 16 + i];
        xy[i * 1024 + tid] = make_float2(v.x, v.y);
        z[i] = v.z;
        mind[i] = __int_as_float(0x7f800000);     // +inf
        const unsigned nr = 16383u - (unsigned)__float_as_int(v.w);
        if (i & 1) npk[i >> 1] |= nr << 16;
        else       npk[i >> 1]  = nr;
        lox = fminf(lox, v.x); hix = fmaxf(hix, v.x);
        loy = fminf(loy, v.y); hiy = fmaxf(hiy, v.y);
        loz = fminf(loz, v.z); hiz = fmaxf(hiz, v.z);
    }
    // bbox -> bf16 rounded OUTWARD (coords >= 0): conservative bound, 3 regs.
    const unsigned pbx = (__float_as_uint(lox) >> 16) |
                         ((((__float_as_uint(hix) + 0xFFFFu) >> 16) << 16));
    const unsigned pby = (__float_as_uint(loy) >> 16) |
                         ((((__float_as_uint(hiy) + 0xFFFFu) >> 16) << 16));
    const unsigned pbz = (__float_as_uint(loz) >> 16) |
                         ((((__float_as_uint(hiz) + 0xFFFFu) >> 16) << 16));

    const float* P = xyz + (size_t)b * N_PTS * 3;
    float cx = P[0], cy = P[1], cz = P[2];
    if (tid == 0) {
        idxf_out[b * M_CENT] = 0.0f;
        newxyz_out[(b * M_CENT) * 3 + 0] = cx;
        newxyz_out[(b * M_CENT) * 3 + 1] = cy;
        newxyz_out[(b * M_CENT) * 3 + 2] = cz;
    }
    __syncthreads();

    float lmax = __int_as_float(0x7f800000);      // lane's cached max mind
    float cwx = 0.f, cwy = 0.f, cwz = 0.f;        // cached wave candidate
    float cwv = __int_as_float(0x7f800000);
    unsigned cpay = 0u;

    const float2* lxyA = xy + tid;                // i=0..7  (ds off <= 57344)
    const float2* lxyB = xy + 8 * 1024 + tid;     // i=8..15

    for (int j = 1; j < M_CENT; ++j) {
        const int par = j & 1;
        // lane-level conservative reject (bit-exact skip: d>=mind for all the
        // lane's points => fminf leaves every mind unchanged; margin 1.5e-5
        // >> worst-case f32 rounding of the bound chain)
        const float blox = __uint_as_float(pbx << 16);
        const float bhix = __uint_as_float(pbx & 0xFFFF0000u);
        const float bloy = __uint_as_float(pby << 16);
        const float bhiy = __uint_as_float(pby & 0xFFFF0000u);
        const float bloz = __uint_as_float(pbz << 16);
        const float bhiz = __uint_as_float(pbz & 0xFFFF0000u);
        float tx = fmaxf(fmaxf(blox - cx, cx - bhix), 0.0f);
        float ty = fmaxf(fmaxf(bloy - cy, cy - bhiy), 0.0f);
        float tz = fmaxf(fmaxf(bloz - cz, cz - bhiz), 0.0f);
        float lb = (tx * tx + ty * ty) + tz * tz;
        const bool need = (lb * 0.999985f) < lmax;

        if (__any(need)) {
            if (need) {                            // exec-masked pass-1
                float bv0 = -1.0f, bv1 = -1.0f;
#pragma unroll
                for (int i = 0; i < 8; i += 2) {
                    const float2 p0 = lxyA[i * 1024];
                    const float2 p1 = lxyA[(i + 1) * 1024];
                    float dx0 = p0.x - cx, dy0 = p0.y - cy, dz0 = z[i] - cz;
                    float dx1 = p1.x - cx, dy1 = p1.y - cy, dz1 = z[i + 1] - cz;
                    float d0 = (dx0 * dx0 + dy0 * dy0) + dz0 * dz0;  // numpy order
                    float d1 = (dx1 * dx1 + dy1 * dy1) + dz1 * dz1;
                    float m0 = fminf(mind[i], d0);
                    float m1 = fminf(mind[i + 1], d1);
                    mind[i] = m0; mind[i + 1] = m1;
                    bv0 = fmaxf(bv0, m0);
                    bv1 = fmaxf(bv1, m1);
                }
#pragma unroll
                for (int i = 0; i < 8; i += 2) {
                    const float2 p0 = lxyB[i * 1024];
                    const float2 p1 = lxyB[(i + 1) * 1024];
                    float dx0 = p0.x - cx, dy0 = p0.y - cy, dz0 = z[i + 8] - cz;
                    float dx1 = p1.x - cx, dy1 = p1.y - cy, dz1 = z[i + 9] - cz;
                    float d0 = (dx0 * dx0 + dy0 * dy0) + dz0 * dz0;
                    float d1 = (dx1 * dx1 + dy1 * dy1) + dz1 * dz1;
                    float m0 = fminf(mind[i + 8], d0);
                    float m1 = fminf(mind[i + 9], d1);
                    mind[i + 8] = m0; mind[i + 9] = m1;
                    bv0 = fmaxf(bv0, m0);
                    bv1 = fmaxf(bv1, m1);
                }
                lmax = fmaxf(bv0, bv1);
            }
            // wave value max (cached lmax for skipped lanes)
            const float wmax = wave64_fmax(lmax);
            // lane-local candidate (only lanes at the max scan their minds)
            unsigned bk = 0u; float wz = 0.f;
            if (lmax == wmax) {
#pragma unroll
                for (int i = 0; i < 16; ++i) {
                    const unsigned nr = (i & 1) ? (npk[i >> 1] >> 16)
                                                : (npk[i >> 1] & 0xFFFFu);
                    const unsigned nk = ((nr << 4) | (unsigned)i) + 1u;
                    const bool c = (mind[i] == wmax) && (nk >= bk);
                    bk = c ? nk : bk;
                    wz = c ? z[i] : wz;
                }
            }
            // wave tie-resolve: max nk (max norig = smallest orig)
            unsigned long long lm = __ballot(bk != 0u);
            unsigned bestnk = 0u; int ol = 0;
            while (lm) {                          // uniform; few iterations
                const int l = (int)__ffsll(lm) - 1;
                lm &= lm - 1;
                const unsigned nkl = (unsigned)__builtin_amdgcn_readlane((int)bk, l);
                if (nkl >= bestnk) { bestnk = nkl; ol = l; }
            }
            const unsigned dec = bestnk - 1u;
            const unsigned bi  = dec & 15u;
            const float2 pw = xy[bi * 1024 + (wid << 6) + ol];  // uniform addr
            cwx = pw.x; cwy = pw.y;
            cwz = __int_as_float(__builtin_amdgcn_readlane(__float_as_int(wz), ol));
            cwv = wmax;
            cpay = dec >> 4;                       // norig
        }
        // unconditional publish of cached candidate (valid when skipped)
        if (lane == 0) {
            wslot[par][wid] = make_float4(cwx, cwy, cwz, cwv);
            wpay[par][wid]  = cpay;
        }
        __syncthreads();

        // cross-wave resolve: ONE b128 read; coords come via readlane.
        const float4 sv = wslot[par][lane & 15];
        const float gmax = row16_fmax(sv.w);
        const unsigned long long tm = __ballot(sv.w == gmax) & 0xFFFFull;
        int winw;
        if (__popcll(tm) == 1) {
            winw = (int)__ffsll(tm) - 1;
        } else {                                   // rare: equal-value slots
            const int sl = lane & 15;
            const float fk = ((tm >> sl) & 1ull)
                           ? (float)(wpay[par][sl] + 1u) : 0.0f;
            const float fm = row16_fmax(fk);       // exact: norig+1 < 2^24
            winw = (int)__ffsll(__ballot(fk == fm) & 0xFFFFull) - 1;
        }
        cx = __int_as_float(__builtin_amdgcn_readlane(__float_as_int(sv.x), winw));
        cy = __int_as_float(__builtin_amdgcn_readlane(__float_as_int(sv.y), winw));
        cz = __int_as_float(__builtin_amdgcn_readlane(__float_as_int(sv.z), winw));
        if (tid == 0) {
            const unsigned norig = wpay[par][winw];
            idxf_out[b * M_CENT + j] = (float)(16383 - (int)norig);
            newxyz_out[(b * M_CENT + j) * 3 + 0] = cx;
            newxyz_out[(b * M_CENT + j) * 3 + 1] = cy;
            newxyz_out[(b * M_CENT + j) * 3 + 2] = cz;
        }
        // single barrier per iteration: next iteration writes parity ^1; a
        // parity slot is re-written only after the next barrier, which
        // happens-after all reads of it.
    }
}

// ---------------------------------------------------------------------------
__global__ __launch_bounds__(256) void ball_kernel(
    const float* __restrict__ xyz,
    const float* __restrict__ newxyz,
    int* __restrict__ nidx)
{
#pragma clang fp contract(off)
    const float R2 = (float)(0.1 * 0.1);
    const int gw   = blockIdx.x * 4 + (threadIdx.x >> 6);
    const int lane = threadIdx.x & 63;
    const int b    = gw >> 10;
    const float* P = xyz + (size_t)b * N_PTS * 3;
    const float cx = newxyz[gw * 3 + 0];
    const float cy = newxyz[gw * 3 + 1];
    const float cz = newxyz[gw * 3 + 2];
    int* out = nidx + gw * K_SMP;

    int cnt = 0, first = -1;
    for (int base = 0; base < N_PTS; base += 64) {
        const int n = base + lane;
        float dx = P[n * 3 + 0] - cx;
        float dy = P[n * 3 + 1] - cy;
        float dz = P[n * 3 + 2] - cz;
        float xx = dx * dx, yy = dy * dy, zz = dz * dz;
        float d2 = (xx + yy) + zz;
        bool inb = d2 < R2;
        unsigned long long mask = __ballot(inb);
        if (mask) {
            if (first < 0) first = base + __ffsll(mask) - 1;
            int before = __popcll(mask & ((1ull << lane) - 1ull));
            int slot = cnt + before;
            if (inb && slot < K_SMP) out[slot] = n;
            cnt += __popcll(mask);
            if (cnt >= K_SMP) break;
        }
    }
    for (int s = cnt + lane; s < K_SMP; s += 64) out[s] = first;
}

// ---------------------------------------------------------------------------
// Weight prep: f32 (OC,IC) -> bf16 (OC,ICP). remap=1 reorders input channels
// from [xyz(3), feat(64)] to [feat(64), xyz(3), pad] to match Xt layout.
__global__ void prep_w(const float* __restrict__ src, short* __restrict__ dst,
                       int OC, int IC, int ICP, int remap)
{
    int i = blockIdx.x * 256 + threadIdx.x;
    if (i >= OC * ICP) return;
    int oc = i / ICP, ic = i - oc * ICP;
    float v = 0.0f;
    if (remap) {
        if (ic < 64)      v = src[oc * IC + 3 + ic];
        else if (ic < 67) v = src[oc * IC + (ic - 64)];
    } else if (ic < IC)   v = src[oc * IC + ic];
    dst[i] = f2bf(v);
}

// feat (B,64,N) -> featT (B,N,64)
__global__ __launch_bounds__(256) void tfeat_kernel(
    const float* __restrict__ feat, float* __restrict__ featT)
{
    __shared__ float t[64][65];
    const int b = blockIdx.y;
    const int n0 = blockIdx.x * 64;
    for (int it = 0; it < 16; ++it) {
        int idx = it * 256 + threadIdx.x;
        int c = idx >> 6, n = idx & 63;
        t[c][n] = feat[((size_t)b * 64 + c) * N_PTS + n0 + n];
    }
    __syncthreads();
    for (int it = 0; it < 16; ++it) {
        int idx = it * 256 + threadIdx.x;
        int n = idx >> 6, c = idx & 63;
        featT[((size_t)b * N_PTS + n0 + n) * 64 + c] = t[c][n];
    }
}

// ---------------------------------------------------------------------------
// MFMA MLP: 64 cols (2 centroids) per block, 4 waves, bf16 16x16x32 MFMA.
__global__ __launch_bounds__(256, 2) void mlp_kernel(
    const float* __restrict__ xyz, const float* __restrict__ feat,
    const float* __restrict__ featT, int useT,
    const float* __restrict__ newxyz, const int* __restrict__ nidx,
    const short* __restrict__ WaB, const float* __restrict__ ba,
    const short* __restrict__ WbB, const float* __restrict__ bb,
    const short* __restrict__ WsB, const float* __restrict__ bs,
    const short* __restrict__ WcB, const float* __restrict__ bc,
    const short* __restrict__ WdB, const float* __restrict__ bd,
    float* __restrict__ pooled)
{
    __shared__ short Xt[64][104];
    __shared__ short Ht[64][136];
    __shared__ short Tt[64][136];

    const int tid = threadIdx.x;
    const int w = tid >> 6, l = tid & 63, l16 = l & 15, kg = l >> 4;
    const int cen0 = blockIdx.x * 2;
    const int b = cen0 >> 10;
    const int ocw = 32 * w;

    {
        const int col = tid >> 2, part = tid & 3;
        const int ci = cen0 + (col >> 5);
        const int nn = nidx[ci * K_SMP + (col & 31)];
        float v[16];
        if (useT) {
            const f32x4* src = (const f32x4*)(featT + ((size_t)b * N_PTS + nn) * 64 + part * 16);
            f32x4 f0 = src[0], f1 = src[1], f2 = src[2], f3 = src[3];
            v[0]=f0[0]; v[1]=f0[1]; v[2]=f0[2]; v[3]=f0[3];
            v[4]=f1[0]; v[5]=f1[1]; v[6]=f1[2]; v[7]=f1[3];
            v[8]=f2[0]; v[9]=f2[1]; v[10]=f2[2]; v[11]=f2[3];
            v[12]=f3[0]; v[13]=f3[1]; v[14]=f3[2]; v[15]=f3[3];
        } else {
            const float* F = feat + (size_t)b * C_FEAT * N_PTS + nn;
#pragma unroll
            for (int q = 0; q < 16; ++q) v[q] = F[(size_t)(part * 16 + q) * N_PTS];
        }
        bf16x8 h0, h1;
#pragma unroll
        for (int q = 0; q < 8; ++q) { h0[q] = f2bf(v[q]); h1[q] = f2bf(v[q + 8]); }
        *(bf16x8*)&Xt[col][part * 16]     = h0;
        *(bf16x8*)&Xt[col][part * 16 + 8] = h1;
        if (part == 0) {
            bf16x8 hx, zv;
#pragma unroll
            for (int q = 0; q < 8; ++q) { hx[q] = 0; zv[q] = 0; }
            hx[0] = f2bf(xyz[((size_t)b * N_PTS + nn) * 3 + 0] - newxyz[ci * 3 + 0]);
            hx[1] = f2bf(xyz[((size_t)b * N_PTS + nn) * 3 + 1] - newxyz[ci * 3 + 1]);
            hx[2] = f2bf(xyz[((size_t)b * N_PTS + nn) * 3 + 2] - newxyz[ci * 3 + 2]);
            *(bf16x8*)&Xt[col][64] = hx;
            *(bf16x8*)&Xt[col][72] = zv;
            *(bf16x8*)&Xt[col][80] = zv;
            *(bf16x8*)&Xt[col][88] = zv;
        }
    }
    __syncthreads();

    f32x4 accA[2][4], accS[2][4];
#pragma unroll
    for (int o = 0; o < 2; ++o)
#pragma unroll
        for (int ct = 0; ct < 4; ++ct) {
#pragma unroll
            for (int r = 0; r < 4; ++r) { accA[o][ct][r] = 0.f; accS[o][ct][r] = 0.f; }
        }
#pragma unroll
    for (int k = 0; k < 3; ++k) {
        bf16x8 xb[4];
#pragma unroll
        for (int ct = 0; ct < 4; ++ct)
            xb[ct] = *(const bf16x8*)&Xt[ct * 16 + l16][k * 32 + kg * 8];
#pragma unroll
        for (int o = 0; o < 2; ++o) {
            const int row = ocw + o * 16 + l16;
            bf16x8 wa  = *(const bf16x8*)(WaB + row * 96 + k * 32 + kg * 8);
            bf16x8 wsv = *(const bf16x8*)(WsB + row * 96 + k * 32 + kg * 8);
#pragma unroll
            for (int ct = 0; ct < 4; ++ct) {
                accA[o][ct] = __builtin_amdgcn_mfma_f32_16x16x32_bf16(wa,  xb[ct], accA[o][ct], 0, 0, 0);
                accS[o][ct] = __builtin_amdgcn_mfma_f32_16x16x32_bf16(wsv, xb[ct], accS[o][ct], 0, 0, 0);
            }
        }
    }
#pragma unroll
    for (int o = 0; o < 2; ++o) {
        const f32x4 bav = *(const f32x4*)(ba + ocw + o * 16 + kg * 4);
#pragma unroll
        for (int ct = 0; ct < 4; ++ct) {
            s16x4 hv;
#pragma unroll
            for (int r = 0; r < 4; ++r) hv[r] = f2bf(fmaxf(accA[o][ct][r] + bav[r], 0.f));
            *(s16x4*)&Ht[ct * 16 + l16][ocw + o * 16 + kg * 4] = hv;
        }
    }
    __syncthreads();

    f32x4 accB[2][4];
#pragma unroll
    for (int o = 0; o < 2; ++o)
#pragma unroll
        for (int ct = 0; ct < 4; ++ct) {
#pragma unroll
            for (int r = 0; r < 4; ++r) accB[o][ct][r] = 0.f;
        }
#pragma unroll
    for (int k = 0; k < 4; ++k) {
        bf16x8 xb[4];
#pragma unroll
        for (int ct = 0; ct < 4; ++ct)
            xb[ct] = *(const bf16x8*)&Ht[ct * 16 + l16][k * 32 + kg * 8];
#pragma unroll
        for (int o = 0; o < 2; ++o) {
            const int row = ocw + o * 16 + l16;
            bf16x8 wbv = *(const bf16x8*)(WbB + row * 128 + k * 32 + kg * 8);
#pragma unroll
            for (int ct = 0; ct < 4; ++ct)
                accB[o][ct] = __builtin_amdgcn_mfma_f32_16x16x32_bf16(wbv, xb[ct], accB[o][ct], 0, 0, 0);
        }
    }
    f32x4 hreg[2][4];
#pragma unroll
    for (int o = 0; o < 2; ++o) {
        const f32x4 bbv = *(const f32x4*)(bb + ocw + o * 16 + kg * 4);
        const f32x4 bsv = *(const f32x4*)(bs + ocw + o * 16 + kg * 4);
#pragma unroll
        for (int ct = 0; ct < 4; ++ct) {
#pragma unroll
            for (int r = 0; r < 4; ++r)
                hreg[o][ct][r] = fmaxf((accB[o][ct][r] + bbv[r]) + (accS[o][ct][r] + bsv[r]), 0.f);
        }
    }
    __syncthreads();
#pragma unroll
    for (int o = 0; o < 2; ++o)
#pragma unroll
        for (int ct = 0; ct < 4; ++ct) {
            s16x4 hv;
#pragma unroll
            for (int r = 0; r < 4; ++r) hv[r] = f2bf(hreg[o][ct][r]);
            *(s16x4*)&Ht[ct * 16 + l16][ocw + o * 16 + kg * 4] = hv;
        }
    __syncthreads();

    f32x4 accD[2][4];
#pragma unroll
    for (int o = 0; o < 2; ++o)
#pragma unroll
        for (int ct = 0; ct < 4; ++ct) {
#pragma unroll
            for (int r = 0; r < 4; ++r) accD[o][ct][r] = 0.f;
        }
    for (int cc = 0; cc < 4; ++cc) {
        f32x4 accC[2][4];
#pragma unroll
        for (int o = 0; o < 2; ++o)
#pragma unroll
            for (int ct = 0; ct < 4; ++ct) {
#pragma unroll
                for (int r = 0; r < 4; ++r) accC[o][ct][r] = 0.f;
            }
#pragma unroll
        for (int k = 0; k < 4; ++k) {
            bf16x8 xb[4];
#pragma unroll
            for (int ct = 0; ct < 4; ++ct)
                xb[ct] = *(const bf16x8*)&Ht[ct * 16 + l16][k * 32 + kg * 8];
#pragma unroll
            for (int o = 0; o < 2; ++o) {
                const int row = cc * 128 + ocw + o * 16 + l16;
                bf16x8 wcv = *(const bf16x8*)(WcB + row * 128 + k * 32 + kg * 8);
#pragma unroll
                for (int ct = 0; ct < 4; ++ct)
                    accC[o][ct] = __builtin_amdgcn_mfma_f32_16x16x32_bf16(wcv, xb[ct], accC[o][ct], 0, 0, 0);
            }
        }
        __syncthreads();
#pragma unroll
        for (int o = 0; o < 2; ++o) {
            const f32x4 bcv = *(const f32x4*)(bc + cc * 128 + ocw + o * 16 + kg * 4);
#pragma unroll
            for (int ct = 0; ct < 4; ++ct) {
                s16x4 tv;
#pragma unroll
                for (int r = 0; r < 4; ++r) tv[r] = f2bf(fmaxf(accC[o][ct][r] + bcv[r], 0.f));
                *(s16x4*)&Tt[ct * 16 + l16][ocw + o * 16 + kg * 4] = tv;
            }
        }
        __syncthreads();
#pragma unroll
        for (int k = 0; k < 4; ++k) {
            bf16x8 tb[4];
#pragma unroll
            for (int ct = 0; ct < 4; ++ct)
                tb[ct] = *(const bf16x8*)&Tt[ct * 16 + l16][k * 32 + kg * 8];
#pragma unroll
            for (int o = 0; o < 2; ++o) {
                const int row = ocw + o * 16 + l16;
                bf16x8 wdv = *(const bf16x8*)(WdB + row * 512 + cc * 128 + k * 32 + kg * 8);
#pragma unroll
                for (int ct = 0; ct < 4; ++ct)
                    accD[o][ct] = __builtin_amdgcn_mfma_f32_16x16x32_bf16(wdv, tb[ct], accD[o][ct], 0, 0, 0);
            }
        }
    }

    const int m0 = cen0 & 1023;
#pragma unroll
    for (int o = 0; o < 2; ++o) {
        const f32x4 bdv = *(const f32x4*)(bd + ocw + o * 16 + kg * 4);
#pragma unroll
        for (int r = 0; r < 4; ++r) {
            float a0 = fmaxf((accD[o][0][r] + bdv[r]) + hreg[o][0][r], 0.f);
            float a1 = fmaxf((accD[o][1][r] + bdv[r]) + hreg[o][1][r], 0.f);
            float a2 = fmaxf((accD[o][2][r] + bdv[r]) + hreg[o][2][r], 0.f);
            float a3 = fmaxf((accD[o][3][r] + bdv[r]) + hreg[o][3][r], 0.f);
            float u0 = fmaxf(a0, a1), u1 = fmaxf(a2, a3);
#pragma unroll
            for (int off = 1; off < 16; off <<= 1) {
                u0 = fmaxf(u0, __shfl_xor(u0, off));
                u1 = fmaxf(u1, __shfl_xor(u1, off));
            }
            if (l16 == 0) {
                const int oc = ocw + o * 16 + kg * 4 + r;
                pooled[((size_t)b * 128 + oc) * 1024 + m0]     = u0;
                pooled[((size_t)b * 128 + oc) * 1024 + m0 + 1] = u1;
            }
        }
    }
}

// ---------------------------------------------------------------------------
extern "C" void kernel_launch(void* const* d_in, const int* in_sizes, int n_in,
                              void* d_out, int out_size, void* d_ws, size_t ws_size,
                              hipStream_t stream)
{
    const float* xyz  = (const float*)d_in[0];
    const float* feat = (const float*)d_in[1];
    const float* Wa = (const float*)d_in[2];   const float* ba = (const float*)d_in[3];
    const float* Wb = (const float*)d_in[4];   const float* bb = (const float*)d_in[5];
    const float* Ws = (const float*)d_in[6];   const float* bs = (const float*)d_in[7];
    const float* Wc = (const float*)d_in[8];   const float* bc = (const float*)d_in[9];
    const float* Wd = (const float*)d_in[10];  const float* bd = (const float*)d_in[11];

    float* out    = (float*)d_out;
    float* newxyz = out;
    float* pooled = out + 4 * 1024 * 3;
    float* idxf   = pooled + 4 * 128 * 1024;

    char* ws = (char*)d_ws;
    float4* gsxyz = (float4*)ws;                 // 1 MiB; reused as nidx after fps
    int*    nidx  = (int*)ws;
    short* WaB = (short*)(ws + (1 << 20));       // 128*96
    short* WsB = WaB + 128 * 96;                 // 128*96
    short* WbB = WsB + 128 * 96;                 // 128*128
    short* WcB = WbB + 128 * 128;                // 512*128
    short* WdB = WcB + 512 * 128;                // 128*512
    int*   ghist = (int*)(WdB + 128 * 512);
    int*   gbase = ghist + 4 * NCELL;
    float* featT = (float*)(ws + (2 << 20));     // 16 MiB, optional

    const size_t need = (size_t)(2 << 20) + (size_t)4 * N_PTS * 64 * 4;
    const int useT = (ws_size >= need) ? 1 : 0;

    prep_w<<<(128 *  96 + 255) / 256, 256, 0, stream>>>(Wa, WaB, 128,  67,  96, 1);
    prep_w<<<(128 *  96 + 255) / 256, 256, 0, stream>>>(Ws, WsB, 128,  67,  96, 1);
    prep_w<<<(128 * 128 + 255) / 256, 256, 0, stream>>>(Wb, WbB, 128, 128, 128, 0);
    prep_w<<<(512 * 128 + 255) / 256, 256, 0, stream>>>(Wc, WcB, 512, 128, 128, 0);
    prep_w<<<(128 * 512 + 255) / 256, 256, 0, stream>>>(Wd, WdB, 128, 512, 512, 0);
    if (useT) tfeat_kernel<<<dim3(N_PTS / 64, 4), 256, 0, stream>>>(feat, featT);

    hist_kernel   <<<4, 1024,  0, stream>>>(xyz, ghist);
    scan_kernel   <<<4, NCELL, 0, stream>>>(ghist, gbase);
    scatter_kernel<<<4, 1024,  0, stream>>>(xyz, gbase, gsxyz);

    fps_kernel<<<4, 1024, 0, stream>>>(xyz, gsxyz, newxyz, idxf);
    ball_kernel<<<1024, 256, 0, stream>>>(xyz, newxyz, nidx);
    mlp_kernel<<<2048, 256, 0, stream>>>(xyz, feat, featT, useT, newxyz, nidx,
                                         WaB, ba, WbB, bb, WsB, bs,
                                         WcB, bc, WdB, bd, pooled);
}

// Round 13
// 1466.261 us; speedup vs baseline: 1.1858x; 1.1858x over previous
//
#include <hip/hip_runtime.h>

#define N_PTS   16384
#define M_CENT  1024
#define K_SMP   32
#define C_FEAT  64
#define NCELL   512

using bf16x8 = __attribute__((ext_vector_type(8))) short;
using s16x4  = __attribute__((ext_vector_type(4))) short;
using f32x4  = __attribute__((ext_vector_type(4))) float;

__device__ inline short f2bf(float f) {            // f32 -> bf16 RNE
    unsigned u = __float_as_uint(f);
    u += 0x7fffu + ((u >> 16) & 1u);
    return (short)(u >> 16);
}

// ---------------------------------------------------------------------------
// DPP max-reductions (VALU pipe) — r10-proven.
#define DPP_SHR1 0x111
#define DPP_SHR2 0x112
#define DPP_SHR4 0x114
#define DPP_SHR8 0x118
#define DPP_BC15 0x142
#define DPP_BC31 0x143

template<int CTRL, int RM>
__device__ __forceinline__ float dppmax(float v) {
    int o = __builtin_amdgcn_update_dpp(__float_as_int(v), __float_as_int(v),
                                        CTRL, RM, 0xF, false);
    return fmaxf(v, __int_as_float(o));
}

__device__ __forceinline__ float wave64_fmax(float v) {
    v = dppmax<DPP_SHR1, 0xF>(v);
    v = dppmax<DPP_SHR2, 0xF>(v);
    v = dppmax<DPP_SHR4, 0xF>(v);
    v = dppmax<DPP_SHR8, 0xF>(v);
    v = dppmax<DPP_BC15, 0xA>(v);
    v = dppmax<DPP_BC31, 0xC>(v);
    return __int_as_float(__builtin_amdgcn_readlane(__float_as_int(v), 63));
}

__device__ __forceinline__ float row16_fmax(float v) {
    v = dppmax<DPP_SHR1, 0xF>(v);
    v = dppmax<DPP_SHR2, 0xF>(v);
    v = dppmax<DPP_SHR4, 0xF>(v);
    v = dppmax<DPP_SHR8, 0xF>(v);
    return __int_as_float(__builtin_amdgcn_readlane(__float_as_int(v), 15));
}

// ---------------------------------------------------------------------------
// Hilbert cell id (8x8x8 = 512 cells). Order affects only speed.
__device__ inline int hcell_of(float x, float y, float z) {
    int xi = (int)(x * 8.0f); xi = xi < 0 ? 0 : (xi > 7 ? 7 : xi);
    int yi = (int)(y * 8.0f); yi = yi < 0 ? 0 : (yi > 7 ? 7 : yi);
    int zi = (int)(z * 8.0f); zi = zi < 0 ? 0 : (zi > 7 ? 7 : zi);
    unsigned X[3] = {(unsigned)xi, (unsigned)yi, (unsigned)zi};
#pragma unroll
    for (unsigned Q = 4; Q > 1; Q >>= 1) {
        unsigned P = Q - 1;
#pragma unroll
        for (int i = 0; i < 3; ++i) {
            if (X[i] & Q) X[0] ^= P;
            else { unsigned t = (X[0] ^ X[i]) & P; X[0] ^= t; X[i] ^= t; }
        }
    }
    X[1] ^= X[0]; X[2] ^= X[1];
    unsigned t = 0;
#pragma unroll
    for (unsigned Q = 4; Q > 1; Q >>= 1)
        if (X[2] & Q) t ^= Q - 1;
    X[0] ^= t; X[1] ^= t; X[2] ^= t;
    int h = 0;
#pragma unroll
    for (int q = 2; q >= 0; --q)
        h = (h << 3) | (((X[0] >> q) & 1) << 2) | (((X[1] >> q) & 1) << 1) | ((X[2] >> q) & 1);
    return h;
}

// ---------------------------------------------------------------------------
__global__ __launch_bounds__(1024) void hist_kernel(
    const float* __restrict__ xyz, int* __restrict__ ghist)
{
    __shared__ int h[NCELL];
    const int b = blockIdx.x, tid = threadIdx.x;
    if (tid < NCELL) h[tid] = 0;
    __syncthreads();
    const float* P = xyz + (size_t)b * N_PTS * 3;
    for (int i = 0; i < 16; ++i) {
        const int p = tid + (i << 10);
        atomicAdd(&h[hcell_of(P[p*3], P[p*3+1], P[p*3+2])], 1);
    }
    __syncthreads();
    if (tid < NCELL) ghist[b * NCELL + tid] = h[tid];
}

__global__ __launch_bounds__(NCELL) void scan_kernel(
    const int* __restrict__ ghist, int* __restrict__ gbase)
{
    __shared__ int h[NCELL];
    const int b = blockIdx.x, t = threadIdx.x;
    h[t] = ghist[b * NCELL + t];
    __syncthreads();
    int s = 0;
    for (int i = 0; i < t; ++i) s += h[i];
    gbase[b * NCELL + t] = s;
}

__global__ __launch_bounds__(1024) void scatter_kernel(
    const float* __restrict__ xyz, int* __restrict__ gbase,
    float4* __restrict__ gsxyz)
{
    const int b = blockIdx.x, tid = threadIdx.x;
    const float* P = xyz + (size_t)b * N_PTS * 3;
    for (int i = 0; i < 16; ++i) {
        const int p = tid + (i << 10);
        float x = P[p*3], y = P[p*3+1], z = P[p*3+2];
        int c = hcell_of(x, y, z);
        int pos = atomicAdd(&gbase[b * NCELL + c], 1);
        gsxyz[(size_t)b * N_PTS + pos] = make_float4(x, y, z, __int_as_float(p));
    }
}

// ---------------------------------------------------------------------------
// FPS, bit-exact pruned. r13 = r10 VERBATIM (best measured: 1234us) except
// the post-barrier resolve: publish ONE float4 {x,y,z,value} (+ side wpay =
// norig, off the broadcast chain); resolve = one ds_read_b128 -> coords in
// registers -> row16 DPP on .w -> ballot -> popc==1 fast path -> 3 readlanes.
// This removes the second dependent LDS read (~120cyc) from the serial chain.
// Rare equal-value slot ties resolved by max norig via wpay (norig unique per
// point; max norig = smallest original idx = numpy first-wins) -> bit-exact.
__global__ __launch_bounds__(1024) void fps_kernel(
    const float* __restrict__ xyz,
    const float4* __restrict__ gsxyz,
    float* __restrict__ newxyz_out,
    float* __restrict__ idxf_out)
{
#pragma clang fp contract(off)
    const int b = blockIdx.x, tid = threadIdx.x;
    const int wid = tid >> 6, lane = tid & 63;
    const float4* S = gsxyz + (size_t)b * N_PTS;

    __shared__ float2 xy[16 * 1024];              // 128 KB
    __shared__ float4 wslot[2][16];               // parity double-buffer
    __shared__ unsigned wpay[2][16];

    float z[16], mind[16];
    unsigned npk[8];                              // norig = 16383-orig, 2/reg
    float lox = 1e30f, hix = -1e30f, loy = 1e30f, hiy = -1e30f, loz = 1e30f, hiz = -1e30f;
#pragma unroll
    for (int i = 0; i < 16; ++i) {
        const float4 v = S[tid * 16 + i];
        xy[i * 1024 + tid] = make_float2(v.x, v.y);
        z[i] = v.z;
        mind[i] = __int_as_float(0x7f800000);     // +inf
        const unsigned nr = 16383u - (unsigned)__float_as_int(v.w);
        if (i & 1) npk[i >> 1] |= nr << 16;
        else       npk[i >> 1]  = nr;
        lox = fminf(lox, v.x); hix = fmaxf(hix, v.x);
        loy = fminf(loy, v.y); hiy = fmaxf(hiy, v.y);
        loz = fminf(loz, v.z); hiz = fmaxf(hiz, v.z);
    }
    // bbox -> bf16 rounded OUTWARD (coords >= 0): conservative bound, 3 regs.
    const unsigned pbx = (__float_as_uint(lox) >> 16) |
                         ((((__float_as_uint(hix) + 0xFFFFu) >> 16) << 16));
    const unsigned pby = (__float_as_uint(loy) >> 16) |
                         ((((__float_as_uint(hiy) + 0xFFFFu) >> 16) << 16));
    const unsigned pbz = (__float_as_uint(loz) >> 16) |
                         ((((__float_as_uint(hiz) + 0xFFFFu) >> 16) << 16));

    const float* P = xyz + (size_t)b * N_PTS * 3;
    float cx = P[0], cy = P[1], cz = P[2];
    if (tid == 0) {
        idxf_out[b * M_CENT] = 0.0f;
        newxyz_out[(b * M_CENT) * 3 + 0] = cx;
        newxyz_out[(b * M_CENT) * 3 + 1] = cy;
        newxyz_out[(b * M_CENT) * 3 + 2] = cz;
    }
    __syncthreads();

    float lmax = __int_as_float(0x7f800000);      // lane's cached max mind
    float cwx = 0.f, cwy = 0.f, cwz = 0.f;        // cached wave candidate
    float cwv = __int_as_float(0x7f800000);
    unsigned cpay = 0u;

    for (int j = 1; j < M_CENT; ++j) {
        const int par = j & 1;
        // lane-level conservative reject (bit-exact skip: d>=mind for all the
        // lane's points => fminf leaves every mind unchanged; margin 1.5e-5
        // >> worst-case f32 rounding of the bound chain)
        const float blox = __uint_as_float(pbx << 16);
        const float bhix = __uint_as_float(pbx & 0xFFFF0000u);
        const float bloy = __uint_as_float(pby << 16);
        const float bhiy = __uint_as_float(pby & 0xFFFF0000u);
        const float bloz = __uint_as_float(pbz << 16);
        const float bhiz = __uint_as_float(pbz & 0xFFFF0000u);
        float tx = fmaxf(fmaxf(blox - cx, cx - bhix), 0.0f);
        float ty = fmaxf(fmaxf(bloy - cy, cy - bhiy), 0.0f);
        float tz = fmaxf(fmaxf(bloz - cz, cz - bhiz), 0.0f);
        float lb = (tx * tx + ty * ty) + tz * tz;

        if (__any((lb * 0.999985f) < lmax)) {
            // pass 1: distances + fmin update, 2-way split max chains (r10)
            float bv0 = -1.0f, bv1 = -1.0f;
#pragma unroll
            for (int i = 0; i < 16; i += 2) {
                const float2 p0 = xy[i * 1024 + tid];
                const float2 p1 = xy[(i + 1) * 1024 + tid];
                float dx0 = p0.x - cx, dy0 = p0.y - cy, dz0 = z[i] - cz;
                float dx1 = p1.x - cx, dy1 = p1.y - cy, dz1 = z[i + 1] - cz;
                float d0 = (dx0 * dx0 + dy0 * dy0) + dz0 * dz0;  // numpy order
                float d1 = (dx1 * dx1 + dy1 * dy1) + dz1 * dz1;
                float m0 = fminf(mind[i], d0);
                float m1 = fminf(mind[i + 1], d1);
                mind[i] = m0; mind[i + 1] = m1;
                bv0 = fmaxf(bv0, m0);
                bv1 = fmaxf(bv1, m1);
            }
            const float bv = fmaxf(bv0, bv1);
            lmax = bv;
            // pass 2: lane-local tie-break (max nk = smallest original idx)
            unsigned bk = 0u; float wz = 0.f;
#pragma unroll
            for (int i = 0; i < 16; ++i) {
                const unsigned nr = (i & 1) ? (npk[i >> 1] >> 16)
                                            : (npk[i >> 1] & 0xFFFFu);
                const unsigned nk = (nr << 4) | (unsigned)i;
                const bool c = (mind[i] == bv) && (nk >= bk);
                bk = c ? nk : bk;
                wz = c ? z[i] : wz;
            }
            // wave max via DPP (VALU), argmax via ballot + scalar readlane
            const float wmax = wave64_fmax(bv);
            unsigned long long m = __ballot(bv == wmax);
            unsigned bestnk = 0u; int ol = 0;
            while (m) {                               // uniform; ~1 iteration
                const int l = (int)__ffsll(m) - 1;
                m &= m - 1;
                const unsigned nkl = (unsigned)__builtin_amdgcn_readlane((int)bk, l);
                if (nkl >= bestnk) { bestnk = nkl; ol = l; }
            }
            const float2 pw = xy[(bestnk & 15u) * 1024 + (wid << 6) + ol];
            cwx = pw.x; cwy = pw.y;
            cwz = __int_as_float(__builtin_amdgcn_readlane(__float_as_int(wz), ol));
            cwv = wmax;
            cpay = bestnk >> 4;                       // norig
        }
        // unconditional publish of cached candidate (valid even when skipped)
        if (lane == 0) {
            wslot[par][wid] = make_float4(cwx, cwy, cwz, cwv);
            wpay[par][wid]  = cpay;
        }
        __syncthreads();

        // cross-wave resolve: ONE b128 read; coords via readlane (no 2nd read)
        const float4 sv = wslot[par][lane & 15];
        const float gmax = row16_fmax(sv.w);
        const unsigned long long tm = __ballot(sv.w == gmax) & 0xFFFFull;
        int winw;
        if (__popcll(tm) == 1) {
            winw = (int)__ffsll(tm) - 1;
        } else {                                   // rare: equal-value slots
            const int sl = lane & 15;
            const float fk = ((tm >> sl) & 1ull)
                           ? (float)(wpay[par][sl] + 1u) : 0.0f;
            const float fm = row16_fmax(fk);       // exact: norig+1 < 2^24
            winw = (int)__ffsll(__ballot(fk == fm) & 0xFFFFull) - 1;
        }
        cx = __int_as_float(__builtin_amdgcn_readlane(__float_as_int(sv.x), winw));
        cy = __int_as_float(__builtin_amdgcn_readlane(__float_as_int(sv.y), winw));
        cz = __int_as_float(__builtin_amdgcn_readlane(__float_as_int(sv.z), winw));
        if (tid == 0) {
            const unsigned norig = wpay[par][winw];
            idxf_out[b * M_CENT + j] = (float)(16383 - (int)norig);
            newxyz_out[(b * M_CENT + j) * 3 + 0] = cx;
            newxyz_out[(b * M_CENT + j) * 3 + 1] = cy;
            newxyz_out[(b * M_CENT + j) * 3 + 2] = cz;
        }
        // single barrier per iteration: parity slots are re-written only
        // after the next barrier, which happens-after all reads of them.
    }
}

// ---------------------------------------------------------------------------
__global__ __launch_bounds__(256) void ball_kernel(
    const float* __restrict__ xyz,
    const float* __restrict__ newxyz,
    int* __restrict__ nidx)
{
#pragma clang fp contract(off)
    const float R2 = (float)(0.1 * 0.1);
    const int gw   = blockIdx.x * 4 + (threadIdx.x >> 6);
    const int lane = threadIdx.x & 63;
    const int b    = gw >> 10;
    const float* P = xyz + (size_t)b * N_PTS * 3;
    const float cx = newxyz[gw * 3 + 0];
    const float cy = newxyz[gw * 3 + 1];
    const float cz = newxyz[gw * 3 + 2];
    int* out = nidx + gw * K_SMP;

    int cnt = 0, first = -1;
    for (int base = 0; base < N_PTS; base += 64) {
        const int n = base + lane;
        float dx = P[n * 3 + 0] - cx;
        float dy = P[n * 3 + 1] - cy;
        float dz = P[n * 3 + 2] - cz;
        float xx = dx * dx, yy = dy * dy, zz = dz * dz;
        float d2 = (xx + yy) + zz;
        bool inb = d2 < R2;
        unsigned long long mask = __ballot(inb);
        if (mask) {
            if (first < 0) first = base + __ffsll(mask) - 1;
            int before = __popcll(mask & ((1ull << lane) - 1ull));
            int slot = cnt + before;
            if (inb && slot < K_SMP) out[slot] = n;
            cnt += __popcll(mask);
            if (cnt >= K_SMP) break;
        }
    }
    for (int s = cnt + lane; s < K_SMP; s += 64) out[s] = first;
}

// ---------------------------------------------------------------------------
// Weight prep: f32 (OC,IC) -> bf16 (OC,ICP). remap=1 reorders input channels
// from [xyz(3), feat(64)] to [feat(64), xyz(3), pad] to match Xt layout.
__global__ void prep_w(const float* __restrict__ src, short* __restrict__ dst,
                       int OC, int IC, int ICP, int remap)
{
    int i = blockIdx.x * 256 + threadIdx.x;
    if (i >= OC * ICP) return;
    int oc = i / ICP, ic = i - oc * ICP;
    float v = 0.0f;
    if (remap) {
        if (ic < 64)      v = src[oc * IC + 3 + ic];
        else if (ic < 67) v = src[oc * IC + (ic - 64)];
    } else if (ic < IC)   v = src[oc * IC + ic];
    dst[i] = f2bf(v);
}

// feat (B,64,N) -> featT (B,N,64)
__global__ __launch_bounds__(256) void tfeat_kernel(
    const float* __restrict__ feat, float* __restrict__ featT)
{
    __shared__ float t[64][65];
    const int b = blockIdx.y;
    const int n0 = blockIdx.x * 64;
    for (int it = 0; it < 16; ++it) {
        int idx = it * 256 + threadIdx.x;
        int c = idx >> 6, n = idx & 63;
        t[c][n] = feat[((size_t)b * 64 + c) * N_PTS + n0 + n];
    }
    __syncthreads();
    for (int it = 0; it < 16; ++it) {
        int idx = it * 256 + threadIdx.x;
        int n = idx >> 6, c = idx & 63;
        featT[((size_t)b * N_PTS + n0 + n) * 64 + c] = t[c][n];
    }
}

// ---------------------------------------------------------------------------
// MFMA MLP: 64 cols (2 centroids) per block, 4 waves, bf16 16x16x32 MFMA.
__global__ __launch_bounds__(256, 2) void mlp_kernel(
    const float* __restrict__ xyz, const float* __restrict__ feat,
    const float* __restrict__ featT, int useT,
    const float* __restrict__ newxyz, const int* __restrict__ nidx,
    const short* __restrict__ WaB, const float* __restrict__ ba,
    const short* __restrict__ WbB, const float* __restrict__ bb,
    const short* __restrict__ WsB, const float* __restrict__ bs,
    const short* __restrict__ WcB, const float* __restrict__ bc,
    const short* __restrict__ WdB, const float* __restrict__ bd,
    float* __restrict__ pooled)
{
    __shared__ short Xt[64][104];
    __shared__ short Ht[64][136];
    __shared__ short Tt[64][136];

    const int tid = threadIdx.x;
    const int w = tid >> 6, l = tid & 63, l16 = l & 15, kg = l >> 4;
    const int cen0 = blockIdx.x * 2;
    const int b = cen0 >> 10;
    const int ocw = 32 * w;

    {
        const int col = tid >> 2, part = tid & 3;
        const int ci = cen0 + (col >> 5);
        const int nn = nidx[ci * K_SMP + (col & 31)];
        float v[16];
        if (useT) {
            const f32x4* src = (const f32x4*)(featT + ((size_t)b * N_PTS + nn) * 64 + part * 16);
            f32x4 f0 = src[0], f1 = src[1], f2 = src[2], f3 = src[3];
            v[0]=f0[0]; v[1]=f0[1]; v[2]=f0[2]; v[3]=f0[3];
            v[4]=f1[0]; v[5]=f1[1]; v[6]=f1[2]; v[7]=f1[3];
            v[8]=f2[0]; v[9]=f2[1]; v[10]=f2[2]; v[11]=f2[3];
            v[12]=f3[0]; v[13]=f3[1]; v[14]=f3[2]; v[15]=f3[3];
        } else {
            const float* F = feat + (size_t)b * C_FEAT * N_PTS + nn;
#pragma unroll
            for (int q = 0; q < 16; ++q) v[q] = F[(size_t)(part * 16 + q) * N_PTS];
        }
        bf16x8 h0, h1;
#pragma unroll
        for (int q = 0; q < 8; ++q) { h0[q] = f2bf(v[q]); h1[q] = f2bf(v[q + 8]); }
        *(bf16x8*)&Xt[col][part * 16]     = h0;
        *(bf16x8*)&Xt[col][part * 16 + 8] = h1;
        if (part == 0) {
            bf16x8 hx, zv;
#pragma unroll
            for (int q = 0; q < 8; ++q) { hx[q] = 0; zv[q] = 0; }
            hx[0] = f2bf(xyz[((size_t)b * N_PTS + nn) * 3 + 0] - newxyz[ci * 3 + 0]);
            hx[1] = f2bf(xyz[((size_t)b * N_PTS + nn) * 3 + 1] - newxyz[ci * 3 + 1]);
            hx[2] = f2bf(xyz[((size_t)b * N_PTS + nn) * 3 + 2] - newxyz[ci * 3 + 2]);
            *(bf16x8*)&Xt[col][64] = hx;
            *(bf16x8*)&Xt[col][72] = zv;
            *(bf16x8*)&Xt[col][80] = zv;
            *(bf16x8*)&Xt[col][88] = zv;
        }
    }
    __syncthreads();

    f32x4 accA[2][4], accS[2][4];
#pragma unroll
    for (int o = 0; o < 2; ++o)
#pragma unroll
        for (int ct = 0; ct < 4; ++ct) {
#pragma unroll
            for (int r = 0; r < 4; ++r) { accA[o][ct][r] = 0.f; accS[o][ct][r] = 0.f; }
        }
#pragma unroll
    for (int k = 0; k < 3; ++k) {
        bf16x8 xb[4];
#pragma unroll
        for (int ct = 0; ct < 4; ++ct)
            xb[ct] = *(const bf16x8*)&Xt[ct * 16 + l16][k * 32 + kg * 8];
#pragma unroll
        for (int o = 0; o < 2; ++o) {
            const int row = ocw + o * 16 + l16;
            bf16x8 wa  = *(const bf16x8*)(WaB + row * 96 + k * 32 + kg * 8);
            bf16x8 wsv = *(const bf16x8*)(WsB + row * 96 + k * 32 + kg * 8);
#pragma unroll
            for (int ct = 0; ct < 4; ++ct) {
                accA[o][ct] = __builtin_amdgcn_mfma_f32_16x16x32_bf16(wa,  xb[ct], accA[o][ct], 0, 0, 0);
                accS[o][ct] = __builtin_amdgcn_mfma_f32_16x16x32_bf16(wsv, xb[ct], accS[o][ct], 0, 0, 0);
            }
        }
    }
#pragma unroll
    for (int o = 0; o < 2; ++o) {
        const f32x4 bav = *(const f32x4*)(ba + ocw + o * 16 + kg * 4);
#pragma unroll
        for (int ct = 0; ct < 4; ++ct) {
            s16x4 hv;
#pragma unroll
            for (int r = 0; r < 4; ++r) hv[r] = f2bf(fmaxf(accA[o][ct][r] + bav[r], 0.f));
            *(s16x4*)&Ht[ct * 16 + l16][ocw + o * 16 + kg * 4] = hv;
        }
    }
    __syncthreads();

    f32x4 accB[2][4];
#pragma unroll
    for (int o = 0; o < 2; ++o)
#pragma unroll
        for (int ct = 0; ct < 4; ++ct) {
#pragma unroll
            for (int r = 0; r < 4; ++r) accB[o][ct][r] = 0.f;
        }
#pragma unroll
    for (int k = 0; k < 4; ++k) {
        bf16x8 xb[4];
#pragma unroll
        for (int ct = 0; ct < 4; ++ct)
            xb[ct] = *(const bf16x8*)&Ht[ct * 16 + l16][k * 32 + kg * 8];
#pragma unroll
        for (int o = 0; o < 2; ++o) {
            const int row = ocw + o * 16 + l16;
            bf16x8 wbv = *(const bf16x8*)(WbB + row * 128 + k * 32 + kg * 8);
#pragma unroll
            for (int ct = 0; ct < 4; ++ct)
                accB[o][ct] = __builtin_amdgcn_mfma_f32_16x16x32_bf16(wbv, xb[ct], accB[o][ct], 0, 0, 0);
        }
    }
    f32x4 hreg[2][4];
#pragma unroll
    for (int o = 0; o < 2; ++o) {
        const f32x4 bbv = *(const f32x4*)(bb + ocw + o * 16 + kg * 4);
        const f32x4 bsv = *(const f32x4*)(bs + ocw + o * 16 + kg * 4);
#pragma unroll
        for (int ct = 0; ct < 4; ++ct) {
#pragma unroll
            for (int r = 0; r < 4; ++r)
                hreg[o][ct][r] = fmaxf((accB[o][ct][r] + bbv[r]) + (accS[o][ct][r] + bsv[r]), 0.f);
        }
    }
    __syncthreads();
#pragma unroll
    for (int o = 0; o < 2; ++o)
#pragma unroll
        for (int ct = 0; ct < 4; ++ct) {
            s16x4 hv;
#pragma unroll
            for (int r = 0; r < 4; ++r) hv[r] = f2bf(hreg[o][ct][r]);
            *(s16x4*)&Ht[ct * 16 + l16][ocw + o * 16 + kg * 4] = hv;
        }
    __syncthreads();

    f32x4 accD[2][4];
#pragma unroll
    for (int o = 0; o < 2; ++o)
#pragma unroll
        for (int ct = 0; ct < 4; ++ct) {
#pragma unroll
            for (int r = 0; r < 4; ++r) accD[o][ct][r] = 0.f;
        }
    for (int cc = 0; cc < 4; ++cc) {
        f32x4 accC[2][4];
#pragma unroll
        for (int o = 0; o < 2; ++o)
#pragma unroll
            for (int ct = 0; ct < 4; ++ct) {
#pragma unroll
                for (int r = 0; r < 4; ++r) accC[o][ct][r] = 0.f;
            }
#pragma unroll
        for (int k = 0; k < 4; ++k) {
            bf16x8 xb[4];
#pragma unroll
            for (int ct = 0; ct < 4; ++ct)
                xb[ct] = *(const bf16x8*)&Ht[ct * 16 + l16][k * 32 + kg * 8];
#pragma unroll
            for (int o = 0; o < 2; ++o) {
                const int row = cc * 128 + ocw + o * 16 + l16;
                bf16x8 wcv = *(const bf16x8*)(WcB + row * 128 + k * 32 + kg * 8);
#pragma unroll
                for (int ct = 0; ct < 4; ++ct)
                    accC[o][ct] = __builtin_amdgcn_mfma_f32_16x16x32_bf16(wcv, xb[ct], accC[o][ct], 0, 0, 0);
            }
        }
        __syncthreads();
#pragma unroll
        for (int o = 0; o < 2; ++o) {
            const f32x4 bcv = *(const f32x4*)(bc + cc * 128 + ocw + o * 16 + kg * 4);
#pragma unroll
            for (int ct = 0; ct < 4; ++ct) {
                s16x4 tv;
#pragma unroll
                for (int r = 0; r < 4; ++r) tv[r] = f2bf(fmaxf(accC[o][ct][r] + bcv[r], 0.f));
                *(s16x4*)&Tt[ct * 16 + l16][ocw + o * 16 + kg * 4] = tv;
            }
        }
        __syncthreads();
#pragma unroll
        for (int k = 0; k < 4; ++k) {
            bf16x8 tb[4];
#pragma unroll
            for (int ct = 0; ct < 4; ++ct)
                tb[ct] = *(const bf16x8*)&Tt[ct * 16 + l16][k * 32 + kg * 8];
#pragma unroll
            for (int o = 0; o < 2; ++o) {
                const int row = ocw + o * 16 + l16;
                bf16x8 wdv = *(const bf16x8*)(WdB + row * 512 + cc * 128 + k * 32 + kg * 8);
#pragma unroll
                for (int ct = 0; ct < 4; ++ct)
                    accD[o][ct] = __builtin_amdgcn_mfma_f32_16x16x32_bf16(wdv, tb[ct], accD[o][ct], 0, 0, 0);
            }
        }
    }

    const int m0 = cen0 & 1023;
#pragma unroll
    for (int o = 0; o < 2; ++o) {
        const f32x4 bdv = *(const f32x4*)(bd + ocw + o * 16 + kg * 4);
#pragma unroll
        for (int r = 0; r < 4; ++r) {
            float a0 = fmaxf((accD[o][0][r] + bdv[r]) + hreg[o][0][r], 0.f);
            float a1 = fmaxf((accD[o][1][r] + bdv[r]) + hreg[o][1][r], 0.f);
            float a2 = fmaxf((accD[o][2][r] + bdv[r]) + hreg[o][2][r], 0.f);
            float a3 = fmaxf((accD[o][3][r] + bdv[r]) + hreg[o][3][r], 0.f);
            float u0 = fmaxf(a0, a1), u1 = fmaxf(a2, a3);
#pragma unroll
            for (int off = 1; off < 16; off <<= 1) {
                u0 = fmaxf(u0, __shfl_xor(u0, off));
                u1 = fmaxf(u1, __shfl_xor(u1, off));
            }
            if (l16 == 0) {
                const int oc = ocw + o * 16 + kg * 4 + r;
                pooled[((size_t)b * 128 + oc) * 1024 + m0]     = u0;
                pooled[((size_t)b * 128 + oc) * 1024 + m0 + 1] = u1;
            }
        }
    }
}

// ---------------------------------------------------------------------------
extern "C" void kernel_launch(void* const* d_in, const int* in_sizes, int n_in,
                              void* d_out, int out_size, void* d_ws, size_t ws_size,
                              hipStream_t stream)
{
    const float* xyz  = (const float*)d_in[0];
    const float* feat = (const float*)d_in[1];
    const float* Wa = (const float*)d_in[2];   const float* ba = (const float*)d_in[3];
    const float* Wb = (const float*)d_in[4];   const float* bb = (const float*)d_in[5];
    const float* Ws = (const float*)d_in[6];   const float* bs = (const float*)d_in[7];
    const float* Wc = (const float*)d_in[8];   const float* bc = (const float*)d_in[9];
    const float* Wd = (const float*)d_in[10];  const float* bd = (const float*)d_in[11];

    float* out    = (float*)d_out;
    float* newxyz = out;
    float* pooled = out + 4 * 1024 * 3;
    float* idxf   = pooled + 4 * 128 * 1024;

    char* ws = (char*)d_ws;
    float4* gsxyz = (float4*)ws;                 // 1 MiB; reused as nidx after fps
    int*    nidx  = (int*)ws;
    short* WaB = (short*)(ws + (1 << 20));       // 128*96
    short* WsB = WaB + 128 * 96;                 // 128*96
    short* WbB = WsB + 128 * 96;                 // 128*128
    short* WcB = WbB + 128 * 128;                // 512*128
    short* WdB = WcB + 512 * 128;                // 128*512
    int*   ghist = (int*)(WdB + 128 * 512);
    int*   gbase = ghist + 4 * NCELL;
    float* featT = (float*)(ws + (2 << 20));     // 16 MiB, optional

    const size_t need = (size_t)(2 << 20) + (size_t)4 * N_PTS * 64 * 4;
    const int useT = (ws_size >= need) ? 1 : 0;

    prep_w<<<(128 *  96 + 255) / 256, 256, 0, stream>>>(Wa, WaB, 128,  67,  96, 1);
    prep_w<<<(128 *  96 + 255) / 256, 256, 0, stream>>>(Ws, WsB, 128,  67,  96, 1);
    prep_w<<<(128 * 128 + 255) / 256, 256, 0, stream>>>(Wb, WbB, 128, 128, 128, 0);
    prep_w<<<(512 * 128 + 255) / 256, 256, 0, stream>>>(Wc, WcB, 512, 128, 128, 0);
    prep_w<<<(128 * 512 + 255) / 256, 256, 0, stream>>>(Wd, WdB, 128, 512, 512, 0);
    if (useT) tfeat_kernel<<<dim3(N_PTS / 64, 4), 256, 0, stream>>>(feat, featT);

    hist_kernel   <<<4, 1024,  0, stream>>>(xyz, ghist);
    scan_kernel   <<<4, NCELL, 0, stream>>>(ghist, gbase);
    scatter_kernel<<<4, 1024,  0, stream>>>(xyz, gbase, gsxyz);

    fps_kernel<<<4, 1024, 0, stream>>>(xyz, gsxyz, newxyz, idxf);
    ball_kernel<<<1024, 256, 0, stream>>>(xyz, newxyz, nidx);
    mlp_kernel<<<2048, 256, 0, stream>>>(xyz, feat, featT, useT, newxyz, nidx,
                                         WaB, ba, WbB, bb, WsB, bs,
                                         WcB, bc, WdB, bd, pooled);
}